// Round 8
// baseline (138.129 us; speedup 1.0000x reference)
//
#include <hip/hip_runtime.h>

typedef float v2f __attribute__((ext_vector_type(2)));

#define HW      1024   // H*W = BN channel count
#define NLAYERS 30
#define TPB     256    // 4 waves = 2 independent wave-PAIRS; 1 channel/pair

// ---------------------------------------------------------------------------
// DPP wave64 sum (pure VALU); lane 63 ends with the wave total.
// ---------------------------------------------------------------------------
template <int CTRL, int RMASK>
__device__ __forceinline__ float dpp_add(float x) {
    int t = __builtin_amdgcn_update_dpp(0, __builtin_bit_cast(int, x),
                                        CTRL, RMASK, 0xf, true);
    return x + __builtin_bit_cast(float, t);
}
__device__ __forceinline__ float wave_sum_l63(float x) {
    x = dpp_add<0x111, 0xf>(x);   // row_shr:1
    x = dpp_add<0x112, 0xf>(x);   // row_shr:2
    x = dpp_add<0x114, 0xf>(x);   // row_shr:4
    x = dpp_add<0x118, 0xf>(x);   // row_shr:8
    x = dpp_add<0x142, 0xa>(x);   // row_bcast15 -> rows 1,3
    x = dpp_add<0x143, 0xc>(x);   // row_bcast31 -> rows 2,3
    return x;                     // lane 63 = total
}

// ---------------------------------------------------------------------------
// 2 waves own one channel (32 elems/thread); the ONLY cross-wave sync is a
// pair-local LDS tag/spin rendezvous — no __syncthreads in the layer loop,
// so pairs free-run and desynchronize, filling each other's reduction-wait
// windows on the SIMD (R5/R7 showed block-wide barriers phase-lock at ~55%
// idle). Protocol: lane63 writes (s,q) then a monotone tag (volatile program
// order + FIFO LDS pipe => tag visible implies data visible). Pairs stay
// within 1 layer of each other (mutual rendezvous per layer), so parity
// double-buffering is race-free.
// Packing: thread u owns e = u + 256k (+128 in .y half), k=0..15 -> c=.x:u,
// .y:u+128 -> ONE packed m2={m[u],m[u+128]} per layer.
// Epilogue algebra (no z storage): dt*relu6(g*z+bb) =
//   med3(gd*m*x1 + (gd*y + bd), 0, 6*dt),  then y' = (1-dt)*y + that.
// XCD swizzle keeps each 64B x/out line on one XCD's L2 (R4: 220->25 MB).
// ---------------------------------------------------------------------------
__global__ __launch_bounds__(TPB) void ode_fused(const float* __restrict__ x,
                                                 const float* __restrict__ delta_t,
                                                 const float* __restrict__ matrices,
                                                 const float* __restrict__ gamma,
                                                 const float* __restrict__ beta,
                                                 float* __restrict__ out) {
    const int bid  = blockIdx.x;          // 0..511
    const int t    = threadIdx.x;         // 0..255
    const int pair = t >> 7;              // 0/1: which channel of this block
    const int u    = t & 127;             // thread index within the pair
    const int w    = u >> 6;              // wave within pair (0/1)
    const int lane = t & 63;
    const int p    = (((bid & 7) << 7) | ((bid >> 3) << 1)) + pair;

    __shared__ float smat[(NLAYERS + 1) * 256];   // +pad row: uncond prefetch
    __shared__ float sdt[NLAYERS + 1];
    __shared__ volatile float red[2][2][4];       // [pair][par][s0,q0,s1,q1]
    __shared__ volatile int  rtag[2][2][2];       // [pair][par][wave]

    for (int i = t; i < NLAYERS * 256; i += TPB) smat[i] = matrices[i];
    if (t < NLAYERS) sdt[t] = __builtin_amdgcn_fmed3f(delta_t[t], 0.0f, 6.0f);
    if (t == 0) sdt[NLAYERS] = 0.0f;
    if (t < 8) ((volatile int*)rtag)[t] = 0;

    // Gather channel p: e = u + 256k (.x) / +128 (.y); stride-4KB scalar
    // loads, served by the owning XCD's L2 after the swizzle.
    v2f x1[16], y[16];
#pragma unroll
    for (int k = 0; k < 16; ++k) {
        const int e0 = u + 256 * k;
        x1[k].x = x[(size_t)e0 * HW + p];
        x1[k].y = x[(size_t)(e0 + 128) * HW + p];
        y[k] = x1[k];
    }

    const float gp = gamma[p];
    const float bp = beta[p];

    __syncthreads();   // once: staged LDS visible; never again in the loop
    float m0 = smat[u], m1 = smat[u + 128];
    float dtl = sdt[0];

    for (int l = 0; l < NLAYERS; ++l) {
        const v2f m2 = {m0, m1};

        // z = fma(m, x1, y), accumulate (sum, sumsq); z not stored.
        v2f sA = {0.f, 0.f}, sB = {0.f, 0.f};
        v2f qA = {0.f, 0.f}, qB = {0.f, 0.f};
#pragma unroll
        for (int k = 0; k < 16; k += 2) {
            const v2f za = __builtin_elementwise_fma(m2, x1[k], y[k]);
            const v2f zb = __builtin_elementwise_fma(m2, x1[k + 1], y[k + 1]);
            sA += za; sB += zb;
            qA = __builtin_elementwise_fma(za, za, qA);
            qB = __builtin_elementwise_fma(zb, zb, qB);
        }
        const v2f sv = sA + sB;
        const v2f qv = qA + qB;
        const float s = wave_sum_l63(sv.x + sv.y);
        const float q = wave_sum_l63(qv.x + qv.y);

        const int par = l & 1;
        if (lane == 63) {
            red[pair][par][2 * w]     = s;   // data first...
            red[pair][par][2 * w + 1] = q;
            rtag[pair][par][w] = l + 1;      // ...then monotone tag
        }
        // Fillers while the partner finishes: next layer's params.
        const float m0n = smat[(l + 1) * 256 + u];
        const float m1n = smat[(l + 1) * 256 + u + 128];
        const float dtn = sdt[l + 1];

        while (rtag[pair][par][w ^ 1] < l + 1) { /* spin: partner pending */ }

        const float S = red[pair][par][0] + red[pair][par][2];
        const float Q = red[pair][par][1] + red[pair][par][3];

        const float mean = S * (1.0f / 4096.0f);
        const float var  = fmaf(-mean, mean, Q * (1.0f / 4096.0f));
        const float rstd = rsqrtf(var + 1e-5f);
        const float g    = gp * rstd;
        const float bb   = fmaf(-mean, g, bp);
        const float gd = g * dtl, bd = bb * dtl, sixdt = 6.0f * dtl;
        const float om = 1.0f - dtl;
        const v2f gd2 = {gd, gd}, bd2 = {bd, bd}, om2 = {om, om};
        const v2f gm2 = {gd * m0, gd * m1};
#pragma unroll
        for (int k = 0; k < 16; ++k) {
            v2f a = __builtin_elementwise_fma(y[k], gd2, bd2);   // gd*y + bd
            a = __builtin_elementwise_fma(x1[k], gm2, a);        // + gd*m*x1
            a.x = __builtin_amdgcn_fmed3f(a.x, 0.0f, sixdt);     // dt*relu6(.)
            a.y = __builtin_amdgcn_fmed3f(a.y, 0.0f, sixdt);
            y[k] = __builtin_elementwise_fma(om2, y[k], a);      // (1-dt)y + a
        }
        m0 = m0n; m1 = m1n; dtl = dtn;
    }

    // Scatter out = y + x1; partial lines merge in the owning XCD's L2.
#pragma unroll
    for (int k = 0; k < 16; ++k) {
        const int e0 = u + 256 * k;
        out[(size_t)e0 * HW + p]         = y[k].x + x1[k].x;
        out[(size_t)(e0 + 128) * HW + p] = y[k].y + x1[k].y;
    }
}

extern "C" void kernel_launch(void* const* d_in, const int* in_sizes, int n_in,
                              void* d_out, int out_size, void* d_ws, size_t ws_size,
                              hipStream_t stream) {
    const float* x        = (const float*)d_in[0];   // [16,256,32,32]
    const float* delta_t  = (const float*)d_in[1];   // [30,1]
    const float* matrices = (const float*)d_in[2];   // [30,1,1,16,16]
    const float* gamma    = (const float*)d_in[3];   // [1024]
    const float* beta     = (const float*)d_in[4];   // [1024]
    float* out = (float*)d_out;

    ode_fused<<<dim3(HW / 2), dim3(TPB), 0, stream>>>(x, delta_t, matrices,
                                                      gamma, beta, out);
}

// Round 9
// 118.099 us; speedup vs baseline: 1.1696x; 1.1696x over previous
//
#include <hip/hip_runtime.h>

typedef float v2f __attribute__((ext_vector_type(2)));

#define HW      1024   // H*W = BN channel count
#define NLAYERS 30
#define TPB     256    // 4 waves; block owns TWO channels, interleaved in time

// ---------------------------------------------------------------------------
// DPP wave64 sum (pure VALU); lane 63 ends with the wave total.
// ---------------------------------------------------------------------------
template <int CTRL, int RMASK>
__device__ __forceinline__ float dpp_add(float x) {
    int t = __builtin_amdgcn_update_dpp(0, __builtin_bit_cast(int, x),
                                        CTRL, RMASK, 0xf, true);
    return x + __builtin_bit_cast(float, t);
}
__device__ __forceinline__ float wave_sum_l63(float x) {
    x = dpp_add<0x111, 0xf>(x);   // row_shr:1
    x = dpp_add<0x112, 0xf>(x);   // row_shr:2
    x = dpp_add<0x114, 0xf>(x);   // row_shr:4
    x = dpp_add<0x118, 0xf>(x);   // row_shr:8
    x = dpp_add<0x142, 0xa>(x);   // row_bcast15 -> rows 1,3
    x = dpp_add<0x143, 0xc>(x);   // row_bcast31 -> rows 2,3
    return x;                     // lane 63 = total
}

// ---------------------------------------------------------------------------
// Fused 30-layer ODE, TWO channels per 4-wave block, TEMPORALLY interleaved
// (unlike R7's simultaneous v2f packing): per layer the wave does
//   [compute+DPP+stash A] -> [compute+DPP+stash B] -> ONE barrier ->
//   [readback+stats+epilogue A] -> [readback+stats+epilogue B].
// A's LDS write->read latency hides under B's compute; barrier events per
// unit work are halved; readback-A latency overlaps epilogue scheduling.
// m[l,c] and dt are channel-independent -> one scalar each serves A and B.
// Element map per channel: thread t owns e = t + 256k (k=0..15) -> c = t.
// Epilogue algebra (no z storage, verified R8): y' = (1-dt)*y +
//   med3(gd*m*x1 + gd*y + bd, 0, 6dt), gd=g*dt, bd=bb*dt.
// XCD swizzle: each 64B x/out line (16 consecutive p) maps to one XCD's L2
// (R4: cut hbm 220->25 MB). Adjacent channels pA,pA+1 -> float2 gather.
// ---------------------------------------------------------------------------
__global__ __launch_bounds__(TPB) void ode_fused(const float* __restrict__ x,
                                                 const float* __restrict__ delta_t,
                                                 const float* __restrict__ matrices,
                                                 const float* __restrict__ gamma,
                                                 const float* __restrict__ beta,
                                                 float* __restrict__ out) {
    const int bid  = blockIdx.x;                     // 0..511
    const int t    = threadIdx.x;                    // 0..255 ; c = t
    const int wid  = t >> 6;                         // 0..3
    const int lane = t & 63;
    const int pA   = ((bid & 7) << 7) | ((bid >> 3) << 1);   // pB = pA+1

    __shared__ float smat[(NLAYERS + 1) * 256];      // +pad row: uncond prefetch
    __shared__ float sdt[NLAYERS + 1];
    __shared__ __align__(16) float2 red[2][2][4];    // [parity][ch][wave]=(s,q)

    for (int i = t; i < NLAYERS * 256; i += TPB) smat[i] = matrices[i];
    if (t < NLAYERS) sdt[t] = __builtin_amdgcn_fmed3f(delta_t[t], 0.0f, 6.0f);
    if (t == 0) sdt[NLAYERS] = 0.0f;

    // Gather both channels with one float2 per element (pA, pA+1 adjacent).
    // v2f pair k2 holds elements e = t+512*k2 (.x) and e+256 (.y); both have
    // c = t (512,256 are multiples of 256).
    const float2* __restrict__ xp = (const float2*)(x + pA);
    v2f xA[8], yA[8], xB[8], yB[8];
#pragma unroll
    for (int k2 = 0; k2 < 8; ++k2) {
        const float2 v0 = xp[(size_t)(t + 512 * k2) * (HW / 2)];
        const float2 v1 = xp[(size_t)(t + 512 * k2 + 256) * (HW / 2)];
        xA[k2].x = v0.x; xA[k2].y = v1.x;
        xB[k2].x = v0.y; xB[k2].y = v1.y;
        yA[k2] = xA[k2];
        yB[k2] = xB[k2];
    }

    const float2 gpv = *(const float2*)(gamma + pA);
    const float2 bpv = *(const float2*)(beta + pA);

    __syncthreads();   // staged params visible
    float m_cur = smat[t];
    float dtl   = sdt[0];

    for (int l = 0; l < NLAYERS; ++l) {
        const v2f m2  = {m_cur, m_cur};
        const int par = l & 1;

        // ---- Channel A: z-stats (z = fma(m,x1,y), not stored) + DPP + stash
        {
            v2f s0 = {0.f, 0.f}, s1 = {0.f, 0.f};
            v2f q0 = {0.f, 0.f}, q1 = {0.f, 0.f};
#pragma unroll
            for (int k = 0; k < 8; k += 2) {
                const v2f za = __builtin_elementwise_fma(m2, xA[k], yA[k]);
                const v2f zb = __builtin_elementwise_fma(m2, xA[k + 1], yA[k + 1]);
                s0 += za; s1 += zb;
                q0 = __builtin_elementwise_fma(za, za, q0);
                q1 = __builtin_elementwise_fma(zb, zb, q1);
            }
            const v2f sv = s0 + s1, qv = q0 + q1;
            const float s = wave_sum_l63(sv.x + sv.y);
            const float q = wave_sum_l63(qv.x + qv.y);
            if (lane == 63) { float2 w; w.x = s; w.y = q; red[par][0][wid] = w; }
        }
        // ---- Channel B: same; A's LDS write latency hides under this.
        {
            v2f s0 = {0.f, 0.f}, s1 = {0.f, 0.f};
            v2f q0 = {0.f, 0.f}, q1 = {0.f, 0.f};
#pragma unroll
            for (int k = 0; k < 8; k += 2) {
                const v2f za = __builtin_elementwise_fma(m2, xB[k], yB[k]);
                const v2f zb = __builtin_elementwise_fma(m2, xB[k + 1], yB[k + 1]);
                s0 += za; s1 += zb;
                q0 = __builtin_elementwise_fma(za, za, q0);
                q1 = __builtin_elementwise_fma(zb, zb, q1);
            }
            const v2f sv = s0 + s1, qv = q0 + q1;
            const float s = wave_sum_l63(sv.x + sv.y);
            const float q = wave_sum_l63(qv.x + qv.y);
            if (lane == 63) { float2 w; w.x = s; w.y = q; red[par][1][wid] = w; }
        }

        const float m_nxt = smat[(l + 1) * 256 + t];   // prefetch, drains w/ barrier
        const float dtn   = sdt[l + 1];
        __syncthreads();

        const float gd_dt = dtl;                 // alias for clarity below
        const float om    = 1.0f - dtl;
        const float sixdt = 6.0f * dtl;
        const v2f om2 = {om, om};

        // ---- Epilogue A (readback B issues early; scheduler interleaves)
        {
            const float4 r0 = *(const float4*)&red[par][0][0];  // s0,q0,s1,q1
            const float4 r1 = *(const float4*)&red[par][0][2];  // s2,q2,s3,q3
            const float S = (r0.x + r0.z) + (r1.x + r1.z);
            const float Q = (r0.y + r0.w) + (r1.y + r1.w);
            const float mean = S * (1.0f / 4096.0f);
            const float var  = fmaf(-mean, mean, Q * (1.0f / 4096.0f));
            const float rstd = rsqrtf(var + 1e-5f);
            const float g    = gpv.x * rstd;
            const float bb   = fmaf(-mean, g, bpv.x);
            const float gd = g * gd_dt, bd = bb * gd_dt;
            const v2f gd2 = {gd, gd}, bd2 = {bd, bd};
            const v2f gm2 = {gd * m_cur, gd * m_cur};
#pragma unroll
            for (int k = 0; k < 8; ++k) {
                v2f a = __builtin_elementwise_fma(yA[k], gd2, bd2);
                a = __builtin_elementwise_fma(xA[k], gm2, a);
                a.x = __builtin_amdgcn_fmed3f(a.x, 0.0f, sixdt);
                a.y = __builtin_amdgcn_fmed3f(a.y, 0.0f, sixdt);
                yA[k] = __builtin_elementwise_fma(om2, yA[k], a);
            }
        }
        // ---- Epilogue B
        {
            const float4 r0 = *(const float4*)&red[par][1][0];
            const float4 r1 = *(const float4*)&red[par][1][2];
            const float S = (r0.x + r0.z) + (r1.x + r1.z);
            const float Q = (r0.y + r0.w) + (r1.y + r1.w);
            const float mean = S * (1.0f / 4096.0f);
            const float var  = fmaf(-mean, mean, Q * (1.0f / 4096.0f));
            const float rstd = rsqrtf(var + 1e-5f);
            const float g    = gpv.y * rstd;
            const float bb   = fmaf(-mean, g, bpv.y);
            const float gd = g * gd_dt, bd = bb * gd_dt;
            const v2f gd2 = {gd, gd}, bd2 = {bd, bd};
            const v2f gm2 = {gd * m_cur, gd * m_cur};
#pragma unroll
            for (int k = 0; k < 8; ++k) {
                v2f a = __builtin_elementwise_fma(yB[k], gd2, bd2);
                a = __builtin_elementwise_fma(xB[k], gm2, a);
                a.x = __builtin_amdgcn_fmed3f(a.x, 0.0f, sixdt);
                a.y = __builtin_amdgcn_fmed3f(a.y, 0.0f, sixdt);
                yB[k] = __builtin_elementwise_fma(om2, yB[k], a);
            }
        }

        m_cur = m_nxt;
        dtl   = dtn;
    }

    // Scatter out = y + x1 as float2 (both channels); lines merge in XCD L2.
    float2* __restrict__ outp = (float2*)(out + pA);
#pragma unroll
    for (int k2 = 0; k2 < 8; ++k2) {
        float2 w0, w1;
        w0.x = yA[k2].x + xA[k2].x;  w0.y = yB[k2].x + xB[k2].x;
        w1.x = yA[k2].y + xA[k2].y;  w1.y = yB[k2].y + xB[k2].y;
        outp[(size_t)(t + 512 * k2) * (HW / 2)]       = w0;
        outp[(size_t)(t + 512 * k2 + 256) * (HW / 2)] = w1;
    }
}

extern "C" void kernel_launch(void* const* d_in, const int* in_sizes, int n_in,
                              void* d_out, int out_size, void* d_ws, size_t ws_size,
                              hipStream_t stream) {
    const float* x        = (const float*)d_in[0];   // [16,256,32,32]
    const float* delta_t  = (const float*)d_in[1];   // [30,1]
    const float* matrices = (const float*)d_in[2];   // [30,1,1,16,16]
    const float* gamma    = (const float*)d_in[3];   // [1024]
    const float* beta     = (const float*)d_in[4];   // [1024]
    float* out = (float*)d_out;

    ode_fused<<<dim3(HW / 2), dim3(TPB), 0, stream>>>(x, delta_t, matrices,
                                                      gamma, beta, out);
}